// Round 2
// baseline (404.814 us; speedup 1.0000x reference)
//
#include <hip/hip_runtime.h>
#include <hip/hip_cooperative_groups.h>

namespace cg = cooperative_groups;

#define LEAKY(v) ((v) > 0.0f ? (v) : 0.2f * (v))

struct P {
    const float* x; const int* row; const int* col;
    const float* W1; const float* b1; const float* W2; const float* b2;
    const float* k1; const float* kb1; const float* k2; const float* kb2;
    const float* k3; const float* kb3; const float* k4; const float* kb4;
    const float* fw1; const float* fb1; const float* fw2; const float* fb2;
    const float* fw3; const float* fb3;
    float* deg; float* agg1; float* agg2; float* xw;
    float* c1; float* c2; float* c3; float* f1; float* f2; float* out;
    int n; int E;
};

// scatter: agg[col] += xw[row] * rsqrt(deg[row])*rsqrt(deg[col]) incl self-loops
__device__ inline void scatter_stage(const P& p, const float* __restrict__ xw,
                                     float* __restrict__ agg, int tid, int NT) {
    int total = (p.E + p.n) * 32;
    for (int t = tid; t < total; t += NT) {
        int e = t >> 5, j = t & 31;
        int r, c;
        if (e < p.E) { r = p.row[e]; c = p.col[e]; }
        else         { r = c = e - p.E; }
        float nrm = (1.0f / sqrtf(p.deg[r])) * (1.0f / sqrtf(p.deg[c]));
        atomicAdd(&agg[c * 32 + j], xw[r * 32 + j] * nrm);
    }
}

__global__ __launch_bounds__(256, 1) void k_all(P p) {
    cg::grid_group grid = cg::this_grid();
    const int tid = blockIdx.x * blockDim.x + threadIdx.x;
    const int NT  = gridDim.x * blockDim.x;   // 65536
    const int n = p.n, E = p.E;

    // ---- Stage A: degree atomics (self-loop + edges) + xw1 = x@W1 (feat 3..5) ----
    for (int i = tid; i < n + E; i += NT) {
        int c = (i < n) ? i : p.col[i - n];
        atomicAdd(&p.deg[c], 1.0f);
    }
    for (int t = tid; t < n * 32; t += NT) {
        int j = t & 31, nn = t >> 5;
        p.xw[t] = p.x[nn*6+3] * p.W1[96+j]
                + p.x[nn*6+4] * p.W1[128+j]
                + p.x[nn*6+5] * p.W1[160+j];
    }
    grid.sync();

    // ---- Stage B: scatter layer 1 -> agg1 ----
    scatter_stage(p, p.xw, p.agg1, tid, NT);
    grid.sync();

    // ---- Stage C: xw2 = leaky(agg1 + b1) @ W2  (overwrites xw) ----
    for (int t = tid; t < n * 32; t += NT) {
        int j = t & 31, nn = t >> 5;
        const float* a = p.agg1 + nn * 32;
        float s = 0.0f;
#pragma unroll
        for (int f = 0; f < 32; ++f) {
            float v = a[f] + p.b1[f];
            v = LEAKY(v);
            s += v * p.W2[f * 32 + j];
        }
        p.xw[t] = s;
    }
    grid.sync();

    // ---- Stage D: scatter layer 2 -> agg2 ----
    scatter_stage(p, p.xw, p.agg2, tid, NT);
    grid.sync();

    // ---- Stage E: conv1 (+b2, leaky on input) + relu + pool -> c1 [3,499,31] ----
    {
        const int Hp = 499, Wo = 31, total = 3 * Hp * Wo;
        for (int t0 = tid; t0 < total; t0 += NT) {
            int ow = t0 % Wo; int t = t0 / Wo; int oh = t % Hp; int co = t / Hp;
            const float* ip = p.agg2 + (2 * oh) * 32 + ow;
            float vals[4][2];
#pragma unroll
            for (int r = 0; r < 4; ++r)
#pragma unroll
                for (int cx = 0; cx < 2; ++cx) {
                    float v = ip[r * 32 + cx] + p.b2[ow + cx];
                    vals[r][cx] = LEAKY(v);
                }
            const float* wp = p.k1 + co * 6;
            float a0 = vals[0][0]*wp[0] + vals[0][1]*wp[1] + vals[1][0]*wp[2]
                     + vals[1][1]*wp[3] + vals[2][0]*wp[4] + vals[2][1]*wp[5];
            float a1 = vals[1][0]*wp[0] + vals[1][1]*wp[1] + vals[2][0]*wp[2]
                     + vals[2][1]*wp[3] + vals[3][0]*wp[4] + vals[3][1]*wp[5];
            float m = fmaxf(a0, a1) + p.kb1[co];
            p.c1[t0] = fmaxf(m, 0.0f);
        }
    }
    grid.sync();

    // ---- Stage F: conv2 -> c2 [6,248,30] ----
    {
        const int CI = 3, Hin = 499, Win = 31, Hp = 248, Wo = 30, total = 6 * Hp * Wo;
        for (int t0 = tid; t0 < total; t0 += NT) {
            int ow = t0 % Wo; int t = t0 / Wo; int oh = t % Hp; int co = t / Hp;
            float a0 = 0.0f, a1 = 0.0f;
            for (int ci = 0; ci < CI; ++ci) {
                const float* ip = p.c1 + (ci * Hin + 2 * oh) * Win + ow;
                const float* wp = p.k2 + (co * CI + ci) * 6;
                float r00 = ip[0],       r01 = ip[1];
                float r10 = ip[Win],     r11 = ip[Win+1];
                float r20 = ip[2*Win],   r21 = ip[2*Win+1];
                float r30 = ip[3*Win],   r31 = ip[3*Win+1];
                a0 += r00*wp[0] + r01*wp[1] + r10*wp[2] + r11*wp[3] + r20*wp[4] + r21*wp[5];
                a1 += r10*wp[0] + r11*wp[1] + r20*wp[2] + r21*wp[3] + r30*wp[4] + r31*wp[5];
            }
            float m = fmaxf(a0, a1) + p.kb2[co];
            p.c2[t0] = fmaxf(m, 0.0f);
        }
    }
    grid.sync();

    // ---- Stage G: conv3 -> c3 [3,123,29] ----
    {
        const int CI = 6, Hin = 248, Win = 30, Hp = 123, Wo = 29, total = 3 * Hp * Wo;
        for (int t0 = tid; t0 < total; t0 += NT) {
            int ow = t0 % Wo; int t = t0 / Wo; int oh = t % Hp; int co = t / Hp;
            float a0 = 0.0f, a1 = 0.0f;
            for (int ci = 0; ci < CI; ++ci) {
                const float* ip = p.c3 /*dummy*/, *dummy = ip; (void)dummy;
                const float* q = p.c2 + (ci * Hin + 2 * oh) * Win + ow;
                const float* wp = p.k3 + (co * CI + ci) * 6;
                float r00 = q[0],       r01 = q[1];
                float r10 = q[Win],     r11 = q[Win+1];
                float r20 = q[2*Win],   r21 = q[2*Win+1];
                float r30 = q[3*Win],   r31 = q[3*Win+1];
                a0 += r00*wp[0] + r01*wp[1] + r10*wp[2] + r11*wp[3] + r20*wp[4] + r21*wp[5];
                a1 += r10*wp[0] + r11*wp[1] + r20*wp[2] + r21*wp[3] + r30*wp[4] + r31*wp[5];
            }
            float m = fmaxf(a0, a1) + p.kb3[co];
            p.c3[t0] = fmaxf(m, 0.0f);
        }
    }
    grid.sync();

    // ---- Stage H: conv4 redundantly per block into LDS, then FC1 -> f1 ----
    __shared__ float lc4[1680];
    {
        const int CI = 3, Hin = 123, Win = 29, Wo = 28;
        for (int t0 = (int)threadIdx.x; t0 < 1680; t0 += (int)blockDim.x) {
            int ow = t0 % Wo; int oh = t0 / Wo;
            float a0 = 0.0f, a1 = 0.0f;
            for (int ci = 0; ci < CI; ++ci) {
                const float* q = p.c3 + (ci * Hin + 2 * oh) * Win + ow;
                const float* wp = p.k4 + ci * 6;
                float r00 = q[0],       r01 = q[1];
                float r10 = q[Win],     r11 = q[Win+1];
                float r20 = q[2*Win],   r21 = q[2*Win+1];
                float r30 = q[3*Win],   r31 = q[3*Win+1];
                a0 += r00*wp[0] + r01*wp[1] + r10*wp[2] + r11*wp[3] + r20*wp[4] + r21*wp[5];
                a1 += r10*wp[0] + r11*wp[1] + r20*wp[2] + r21*wp[3] + r30*wp[4] + r31*wp[5];
            }
            float m = fmaxf(a0, a1) + p.kb4[0];
            lc4[t0] = fmaxf(m, 0.0f);
        }
        __syncthreads();
        // FC1: 1024 rows, one wave per row (256 blocks x 4 waves)
        int wv = threadIdx.x >> 6, lane = threadIdx.x & 63;
        int o = blockIdx.x * 4 + wv;
        const float* wr = p.fw1 + (size_t)o * 1680;
        float s = 0.0f;
        for (int i = lane; i < 1680; i += 64) s += lc4[i] * wr[i];
#pragma unroll
        for (int off = 32; off > 0; off >>= 1) s += __shfl_down(s, off, 64);
        if (lane == 0) p.f1[o] = s + p.fb1[o];
    }
    grid.sync();

    // ---- Stage I: FC2 (1024x1024) -> f2 ----
    {
        int wv = threadIdx.x >> 6, lane = threadIdx.x & 63;
        int o = blockIdx.x * 4 + wv;
        const float* wr = p.fw2 + (size_t)o * 1024;
        float s = 0.0f;
        for (int i = lane; i < 1024; i += 64) s += p.f1[i] * wr[i];
#pragma unroll
        for (int off = 32; off > 0; off >>= 1) s += __shfl_down(s, off, 64);
        if (lane == 0) p.f2[o] = s + p.fb2[o];
    }
    grid.sync();

    // ---- Stage J: FC3 (64x1024) -> out ----
    {
        int wv = threadIdx.x >> 6, lane = threadIdx.x & 63;
        int o = blockIdx.x * 4 + wv;
        if (o < 64) {
            const float* wr = p.fw3 + (size_t)o * 1024;
            float s = 0.0f;
            for (int i = lane; i < 1024; i += 64) s += p.f2[i] * wr[i];
#pragma unroll
            for (int off = 32; off > 0; off >>= 1) s += __shfl_down(s, off, 64);
            if (lane == 0) p.out[o] = s + p.fb3[o];
        }
    }
}

extern "C" void kernel_launch(void* const* d_in, const int* in_sizes, int n_in,
                              void* d_out, int out_size, void* d_ws, size_t ws_size,
                              hipStream_t stream) {
    P p;
    p.x   = (const float*)d_in[0];
    const int* ei = (const int*)d_in[1];
    p.W1  = (const float*)d_in[2];
    p.b1  = (const float*)d_in[3];
    p.W2  = (const float*)d_in[4];
    p.b2  = (const float*)d_in[5];
    p.k1  = (const float*)d_in[6];
    p.kb1 = (const float*)d_in[7];
    p.k2  = (const float*)d_in[8];
    p.kb2 = (const float*)d_in[9];
    p.k3  = (const float*)d_in[10];
    p.kb3 = (const float*)d_in[11];
    p.k4  = (const float*)d_in[12];
    p.kb4 = (const float*)d_in[13];
    p.fw1 = (const float*)d_in[14];
    p.fb1 = (const float*)d_in[15];
    p.fw2 = (const float*)d_in[16];
    p.fb2 = (const float*)d_in[17];
    p.fw3 = (const float*)d_in[18];
    p.fb3 = (const float*)d_in[19];

    p.n = in_sizes[0] / 6;        // 1000
    p.E = in_sizes[1] / 2;        // 8000
    p.row = ei;
    p.col = ei + p.E;

    float* ws = (float*)d_ws;
    p.deg  = ws;                  // 1024
    p.agg1 = ws + 1024;           // 32000
    p.agg2 = p.agg1 + 32000;      // 32000
    p.xw   = p.agg2 + 32000;      // 32000
    p.c1   = p.xw + 32000;        // 3*499*31 = 46407
    p.c2   = p.c1 + 46407;        // 6*248*30 = 44640
    p.c3   = p.c2 + 44640;        // 3*123*29 = 10701
    p.f1   = p.c3 + 10701;        // 1024
    p.f2   = p.f1 + 1024;         // 1024
    p.out  = (float*)d_out;

    // zero deg + agg1 + agg2 (contiguous): (1024 + 64000) floats
    hipMemsetAsync(d_ws, 0, (1024 + 64000) * sizeof(float), stream);

    void* args[] = { &p };
    hipLaunchCooperativeKernel((const void*)k_all, dim3(256), dim3(256),
                               args, 0, stream);
}

// Round 3
// 234.648 us; speedup vs baseline: 1.7252x; 1.7252x over previous
//
#include <hip/hip_runtime.h>

#define LEAKY(v) ((v) > 0.0f ? (v) : 0.2f * (v))

// ---- K1: degree atomics (edges only; +1 self-loop folded into rsqrt later),
//          zero agg1/agg2, xw1 = x@W1 (features 3..5 only) ----
__global__ void k1_prep(const float* __restrict__ x, const int* __restrict__ col,
                        const float* __restrict__ W1, float* __restrict__ deg,
                        float* __restrict__ aggs /*agg1,agg2 contiguous*/,
                        float* __restrict__ xw, int n, int E) {
    int tid = blockIdx.x * blockDim.x + threadIdx.x;
    int NT = gridDim.x * blockDim.x;
    for (int i = tid; i < 2 * n * 32; i += NT) aggs[i] = 0.0f;
    for (int e = tid; e < E; e += NT) atomicAdd(&deg[col[e]], 1.0f);
    for (int t = tid; t < n * 32; t += NT) {
        int j = t & 31, nn = t >> 5;
        xw[t] = x[nn*6+3] * W1[96+j]
              + x[nn*6+4] * W1[128+j]
              + x[nn*6+5] * W1[160+j];
    }
}

// ---- scatter: agg[col] += xw[row] * rsqrt(deg[row]+1)*rsqrt(deg[col]+1),
//      incl. self-loops (e >= E) ----
__global__ void k_scatter(const float* __restrict__ xw, const float* __restrict__ deg,
                          const int* __restrict__ row, const int* __restrict__ col,
                          float* __restrict__ agg, int E, int n) {
    int tid = blockIdx.x * blockDim.x + threadIdx.x;
    int total = (E + n) * 32;
    if (tid >= total) return;
    int e = tid >> 5, j = tid & 31;
    int r, c; float nrm;
    if (e < E) {
        r = row[e]; c = col[e];
        nrm = (1.0f / sqrtf(deg[r] + 1.0f)) * (1.0f / sqrtf(deg[c] + 1.0f));
    } else {
        r = c = e - E;
        nrm = 1.0f / (deg[r] + 1.0f);
    }
    atomicAdd(&agg[c * 32 + j], xw[r * 32 + j] * nrm);
}

// ---- K3: xw = leaky(agg1 + b1) @ W2 ----
__global__ void k3_xw2(const float* __restrict__ agg1, const float* __restrict__ b1,
                       const float* __restrict__ W2, float* __restrict__ xw, int n) {
    int tid = blockIdx.x * blockDim.x + threadIdx.x;
    if (tid >= n * 32) return;
    int j = tid & 31, nn = tid >> 5;
    const float* a = agg1 + nn * 32;
    float s = 0.0f;
#pragma unroll
    for (int f = 0; f < 32; ++f) {
        float v = a[f] + b1[f];
        v = LEAKY(v);
        s += v * W2[f * 32 + j];
    }
    xw[tid] = s;
}

// ---- K5: conv1 (+b2, leaky on input) + relu + pool -> c1 [3,499,31] ----
__global__ void k5_conv1(const float* __restrict__ h2, const float* __restrict__ b2,
                         const float* __restrict__ w, const float* __restrict__ bias,
                         float* __restrict__ out) {
    const int Hp = 499, Wo = 31, total = 3 * Hp * Wo;
    int t0 = blockIdx.x * blockDim.x + threadIdx.x;
    if (t0 >= total) return;
    int ow = t0 % Wo; int t = t0 / Wo; int oh = t % Hp; int co = t / Hp;
    const float* ip = h2 + (2 * oh) * 32 + ow;
    float vals[4][2];
#pragma unroll
    for (int r = 0; r < 4; ++r)
#pragma unroll
        for (int cx = 0; cx < 2; ++cx) {
            float v = ip[r * 32 + cx] + b2[ow + cx];
            vals[r][cx] = LEAKY(v);
        }
    const float* wp = w + co * 6;
    float a0 = vals[0][0]*wp[0] + vals[0][1]*wp[1] + vals[1][0]*wp[2]
             + vals[1][1]*wp[3] + vals[2][0]*wp[4] + vals[2][1]*wp[5];
    float a1 = vals[1][0]*wp[0] + vals[1][1]*wp[1] + vals[2][0]*wp[2]
             + vals[2][1]*wp[3] + vals[3][0]*wp[4] + vals[3][1]*wp[5];
    float m = fmaxf(a0, a1) + bias[co];
    out[t0] = fmaxf(m, 0.0f);
}

// ---- K6: conv2 -> c2 [6,248,30] ----
__global__ void k6_conv2(const float* __restrict__ in, const float* __restrict__ w,
                         const float* __restrict__ bias, float* __restrict__ out) {
    const int CI = 3, Hin = 499, Win = 31, Hp = 248, Wo = 30, total = 6 * Hp * Wo;
    int t0 = blockIdx.x * blockDim.x + threadIdx.x;
    if (t0 >= total) return;
    int ow = t0 % Wo; int t = t0 / Wo; int oh = t % Hp; int co = t / Hp;
    float a0 = 0.0f, a1 = 0.0f;
#pragma unroll
    for (int ci = 0; ci < CI; ++ci) {
        const float* q = in + (ci * Hin + 2 * oh) * Win + ow;
        const float* wp = w + (co * CI + ci) * 6;
        float r00 = q[0],     r01 = q[1];
        float r10 = q[Win],   r11 = q[Win+1];
        float r20 = q[2*Win], r21 = q[2*Win+1];
        float r30 = q[3*Win], r31 = q[3*Win+1];
        a0 += r00*wp[0] + r01*wp[1] + r10*wp[2] + r11*wp[3] + r20*wp[4] + r21*wp[5];
        a1 += r10*wp[0] + r11*wp[1] + r20*wp[2] + r21*wp[3] + r30*wp[4] + r31*wp[5];
    }
    float m = fmaxf(a0, a1) + bias[co];
    out[t0] = fmaxf(m, 0.0f);
}

// ---- K7: fused conv3 + conv4 (redundant per block, in LDS) + FC1 (4 rows/block) ----
__global__ __launch_bounds__(256) void k7_conv34_fc1(
        const float* __restrict__ c2, const float* __restrict__ k3,
        const float* __restrict__ kb3, const float* __restrict__ k4,
        const float* __restrict__ kb4, const float* __restrict__ fw1,
        const float* __restrict__ fb1, float* __restrict__ f1) {
    __shared__ float lc3[3 * 123 * 29];   // 10701
    __shared__ float lc4[1680];
    // conv3: c2 [6,248,30] -> lc3 [3,123,29]
    {
        const int CI = 6, Hin = 248, Win = 30, Hp = 123, Wo = 29, total = 3 * Hp * Wo;
        for (int t0 = (int)threadIdx.x; t0 < total; t0 += 256) {
            int ow = t0 % Wo; int t = t0 / Wo; int oh = t % Hp; int co = t / Hp;
            float a0 = 0.0f, a1 = 0.0f;
#pragma unroll
            for (int ci = 0; ci < CI; ++ci) {
                const float* q = c2 + (ci * Hin + 2 * oh) * Win + ow;
                const float* wp = k3 + (co * CI + ci) * 6;
                float r00 = q[0],     r01 = q[1];
                float r10 = q[Win],   r11 = q[Win+1];
                float r20 = q[2*Win], r21 = q[2*Win+1];
                float r30 = q[3*Win], r31 = q[3*Win+1];
                a0 += r00*wp[0] + r01*wp[1] + r10*wp[2] + r11*wp[3] + r20*wp[4] + r21*wp[5];
                a1 += r10*wp[0] + r11*wp[1] + r20*wp[2] + r21*wp[3] + r30*wp[4] + r31*wp[5];
            }
            float m = fmaxf(a0, a1) + kb3[co];
            lc3[t0] = fmaxf(m, 0.0f);
        }
    }
    __syncthreads();
    // conv4: lc3 [3,123,29] -> lc4 [60,28]
    {
        const int CI = 3, Hin = 123, Win = 29, Wo = 28;
        for (int t0 = (int)threadIdx.x; t0 < 1680; t0 += 256) {
            int ow = t0 % Wo; int oh = t0 / Wo;
            float a0 = 0.0f, a1 = 0.0f;
#pragma unroll
            for (int ci = 0; ci < CI; ++ci) {
                const float* q = lc3 + (ci * Hin + 2 * oh) * Win + ow;
                const float* wp = k4 + ci * 6;
                float r00 = q[0],     r01 = q[1];
                float r10 = q[Win],   r11 = q[Win+1];
                float r20 = q[2*Win], r21 = q[2*Win+1];
                float r30 = q[3*Win], r31 = q[3*Win+1];
                a0 += r00*wp[0] + r01*wp[1] + r10*wp[2] + r11*wp[3] + r20*wp[4] + r21*wp[5];
                a1 += r10*wp[0] + r11*wp[1] + r20*wp[2] + r21*wp[3] + r30*wp[4] + r31*wp[5];
            }
            float m = fmaxf(a0, a1) + kb4[0];
            lc4[t0] = fmaxf(m, 0.0f);
        }
    }
    __syncthreads();
    // FC1: rows o = blockIdx*4 + wave
    int wv = threadIdx.x >> 6, lane = threadIdx.x & 63;
    int o = blockIdx.x * 4 + wv;
    const float* wr = fw1 + (size_t)o * 1680;
    float s = 0.0f;
    for (int i = lane; i < 1680; i += 64) s += lc4[i] * wr[i];
#pragma unroll
    for (int off = 32; off > 0; off >>= 1) s += __shfl_down(s, off, 64);
    if (lane == 0) f1[o] = s + fb1[o];
}

// ---- FC (generic): rows o = blockIdx*4 + wave, one wave per row ----
__global__ __launch_bounds__(256) void k_fc(const float* __restrict__ v,
                                            const float* __restrict__ w,
                                            const float* __restrict__ b,
                                            float* __restrict__ out, int IN) {
    int wv = threadIdx.x >> 6, lane = threadIdx.x & 63;
    int o = blockIdx.x * 4 + wv;
    const float* wr = w + (size_t)o * IN;
    float s = 0.0f;
    for (int i = lane; i < IN; i += 64) s += v[i] * wr[i];
#pragma unroll
    for (int off = 32; off > 0; off >>= 1) s += __shfl_down(s, off, 64);
    if (lane == 0) out[o] = s + b[o];
}

extern "C" void kernel_launch(void* const* d_in, const int* in_sizes, int n_in,
                              void* d_out, int out_size, void* d_ws, size_t ws_size,
                              hipStream_t stream) {
    const float* x   = (const float*)d_in[0];
    const int*   ei  = (const int*)d_in[1];
    const float* W1  = (const float*)d_in[2];
    const float* b1  = (const float*)d_in[3];
    const float* W2  = (const float*)d_in[4];
    const float* b2  = (const float*)d_in[5];
    const float* k1  = (const float*)d_in[6];
    const float* kb1 = (const float*)d_in[7];
    const float* k2  = (const float*)d_in[8];
    const float* kb2 = (const float*)d_in[9];
    const float* k3  = (const float*)d_in[10];
    const float* kb3 = (const float*)d_in[11];
    const float* k4  = (const float*)d_in[12];
    const float* kb4 = (const float*)d_in[13];
    const float* fw1 = (const float*)d_in[14];
    const float* fb1 = (const float*)d_in[15];
    const float* fw2 = (const float*)d_in[16];
    const float* fb2 = (const float*)d_in[17];
    const float* fw3 = (const float*)d_in[18];
    const float* fb3 = (const float*)d_in[19];

    int n = in_sizes[0] / 6;       // 1000
    int E = in_sizes[1] / 2;       // 8000
    const int* row = ei;
    const int* col = ei + E;

    float* ws   = (float*)d_ws;
    float* deg  = ws;              // 1024
    float* agg1 = ws + 1024;       // 32000  (agg1+agg2 contiguous for K1 zeroing)
    float* agg2 = agg1 + 32000;    // 32000
    float* xw   = agg2 + 32000;    // 32000
    float* c1   = xw + 32000;      // 3*499*31 = 46407
    float* c2   = c1 + 46407;      // 6*248*30 = 44640
    float* f1   = c2 + 44640;      // 1024
    float* f2   = f1 + 1024;       // 1024

    const int B = 256;

    hipMemsetAsync(deg, 0, n * sizeof(float), stream);
    k1_prep<<<256, B, 0, stream>>>(x, col, W1, deg, agg1, xw, n, E);
    int st = (E + n) * 32;
    k_scatter<<<(st + B - 1) / B, B, 0, stream>>>(xw, deg, row, col, agg1, E, n);
    k3_xw2<<<(n * 32 + B - 1) / B, B, 0, stream>>>(agg1, b1, W2, xw, n);
    k_scatter<<<(st + B - 1) / B, B, 0, stream>>>(xw, deg, row, col, agg2, E, n);
    k5_conv1<<<(3 * 499 * 31 + B - 1) / B, B, 0, stream>>>(agg2, b2, k1, kb1, c1);
    k6_conv2<<<(6 * 248 * 30 + B - 1) / B, B, 0, stream>>>(c1, k2, kb2, c2);
    k7_conv34_fc1<<<256, B, 0, stream>>>(c2, k3, kb3, k4, kb4, fw1, fb1, f1);
    k_fc<<<256, B, 0, stream>>>(f1, fw2, fb2, f2, 1024);
    k_fc<<<16, B, 0, stream>>>(f2, fw3, fb3, (float*)d_out, 1024);
}

// Round 4
// 187.407 us; speedup vs baseline: 2.1601x; 1.2521x over previous
//
#include <hip/hip_runtime.h>

#define LEAKY(v) ((v) > 0.0f ? (v) : 0.2f * (v))

// ---- K1: zero agg1/agg2, degree atomics (edges only; self-loop folded as +1),
//          xw1 = x@W1 (features 3..5 only; 0..2 zeroed by forward) ----
__global__ void k1_prep(const float* __restrict__ x, const int* __restrict__ col,
                        const float* __restrict__ W1, float* __restrict__ deg,
                        float* __restrict__ aggs /*agg1,agg2 contiguous*/,
                        float* __restrict__ xw, int n, int E) {
    int tid = blockIdx.x * blockDim.x + threadIdx.x;
    int NT = gridDim.x * blockDim.x;
    for (int i = tid; i < 2 * n * 32; i += NT) aggs[i] = 0.0f;
    for (int e = tid; e < E; e += NT) atomicAdd(&deg[col[e]], 1.0f);
    for (int t = tid; t < n * 32; t += NT) {
        int j = t & 31, nn = t >> 5;
        xw[t] = x[nn*6+3] * W1[96+j]
              + x[nn*6+4] * W1[128+j]
              + x[nn*6+5] * W1[160+j];
    }
}

// ---- scatter: agg[col] += xw[row] * rsqrt(deg[row]+1)*rsqrt(deg[col]+1),
//      incl. self-loops (e >= E) ----
__global__ void k_scatter(const float* __restrict__ xw, const float* __restrict__ deg,
                          const int* __restrict__ row, const int* __restrict__ col,
                          float* __restrict__ agg, int E, int n) {
    int tid = blockIdx.x * blockDim.x + threadIdx.x;
    int total = (E + n) * 32;
    if (tid >= total) return;
    int e = tid >> 5, j = tid & 31;
    int r, c; float nrm;
    if (e < E) {
        r = row[e]; c = col[e];
        nrm = (1.0f / sqrtf(deg[r] + 1.0f)) * (1.0f / sqrtf(deg[c] + 1.0f));
    } else {
        r = c = e - E;
        nrm = 1.0f / (deg[r] + 1.0f);
    }
    atomicAdd(&agg[c * 32 + j], xw[r * 32 + j] * nrm);
}

// ---- K3: xw = leaky(agg1 + b1) @ W2 ----
__global__ void k3_xw2(const float* __restrict__ agg1, const float* __restrict__ b1,
                       const float* __restrict__ W2, float* __restrict__ xw, int n) {
    int tid = blockIdx.x * blockDim.x + threadIdx.x;
    if (tid >= n * 32) return;
    int j = tid & 31, nn = tid >> 5;
    const float* a = agg1 + nn * 32;
    float s = 0.0f;
#pragma unroll
    for (int f = 0; f < 32; ++f) {
        float v = a[f] + b1[f];
        v = LEAKY(v);
        s += v * W2[f * 32 + j];
    }
    xw[tid] = s;
}

// ---- K5: conv1 (+b2, leaky on input) + relu + pool -> c1 [3,499,31] ----
__global__ void k5_conv1(const float* __restrict__ h2, const float* __restrict__ b2,
                         const float* __restrict__ w, const float* __restrict__ bias,
                         float* __restrict__ out) {
    const int Hp = 499, Wo = 31, total = 3 * Hp * Wo;
    int t0 = blockIdx.x * blockDim.x + threadIdx.x;
    if (t0 >= total) return;
    int ow = t0 % Wo; int t = t0 / Wo; int oh = t % Hp; int co = t / Hp;
    const float* ip = h2 + (2 * oh) * 32 + ow;
    float vals[4][2];
#pragma unroll
    for (int r = 0; r < 4; ++r)
#pragma unroll
        for (int cx = 0; cx < 2; ++cx) {
            float v = ip[r * 32 + cx] + b2[ow + cx];
            vals[r][cx] = LEAKY(v);
        }
    const float* wp = w + co * 6;
    float a0 = vals[0][0]*wp[0] + vals[0][1]*wp[1] + vals[1][0]*wp[2]
             + vals[1][1]*wp[3] + vals[2][0]*wp[4] + vals[2][1]*wp[5];
    float a1 = vals[1][0]*wp[0] + vals[1][1]*wp[1] + vals[2][0]*wp[2]
             + vals[2][1]*wp[3] + vals[3][0]*wp[4] + vals[3][1]*wp[5];
    float m = fmaxf(a0, a1) + bias[co];
    out[t0] = fmaxf(m, 0.0f);
}

// ---- K6: conv2 -> c2 [6,248,30] ----
__global__ void k6_conv2(const float* __restrict__ in, const float* __restrict__ w,
                         const float* __restrict__ bias, float* __restrict__ out) {
    const int CI = 3, Hin = 499, Win = 31, Hp = 248, Wo = 30, total = 6 * Hp * Wo;
    int t0 = blockIdx.x * blockDim.x + threadIdx.x;
    if (t0 >= total) return;
    int ow = t0 % Wo; int t = t0 / Wo; int oh = t % Hp; int co = t / Hp;
    float a0 = 0.0f, a1 = 0.0f;
#pragma unroll
    for (int ci = 0; ci < CI; ++ci) {
        const float* q = in + (ci * Hin + 2 * oh) * Win + ow;
        const float* wp = w + (co * CI + ci) * 6;
        float r00 = q[0],     r01 = q[1];
        float r10 = q[Win],   r11 = q[Win+1];
        float r20 = q[2*Win], r21 = q[2*Win+1];
        float r30 = q[3*Win], r31 = q[3*Win+1];
        a0 += r00*wp[0] + r01*wp[1] + r10*wp[2] + r11*wp[3] + r20*wp[4] + r21*wp[5];
        a1 += r10*wp[0] + r11*wp[1] + r20*wp[2] + r21*wp[3] + r30*wp[4] + r31*wp[5];
    }
    float m = fmaxf(a0, a1) + bias[co];
    out[t0] = fmaxf(m, 0.0f);
}

// ---- K7: fused conv3+conv4 -> c4 [60,28], non-redundant across blocks.
//      One thread per c4 output; c3 values recomputed on the fly (~3.8x on a
//      tiny stage; all c2 reads L1/L2-hot). ----
__global__ void k7_conv34(const float* __restrict__ c2, const float* __restrict__ k3,
                          const float* __restrict__ kb3, const float* __restrict__ k4,
                          const float* __restrict__ kb4, float* __restrict__ c4) {
    int t0 = blockIdx.x * blockDim.x + threadIdx.x;
    if (t0 >= 60 * 28) return;
    const int Wo4 = 28;
    int ow4 = t0 % Wo4, oh4 = t0 / Wo4;
    const int Hin2 = 248, Win2 = 30;   // c2 dims
    float a4_0 = 0.0f, a4_1 = 0.0f;    // two conv4 pooling positions
#pragma unroll
    for (int ci3 = 0; ci3 < 3; ++ci3) {
        float c3v[4][2];
#pragma unroll
        for (int hr = 0; hr < 4; ++hr) {
#pragma unroll
            for (int wc = 0; wc < 2; ++wc) {
                int h3 = 2 * oh4 + hr;      // c3 row
                int w3 = ow4 + wc;          // c3 col
                float b0 = 0.0f, b1 = 0.0f; // conv3's two pooling positions
#pragma unroll
                for (int ci2 = 0; ci2 < 6; ++ci2) {
                    const float* q = c2 + (ci2 * Hin2 + 2 * h3) * Win2 + w3;
                    const float* wp = k3 + (ci3 * 6 + ci2) * 6;
                    float r00 = q[0],       r01 = q[1];
                    float r10 = q[Win2],    r11 = q[Win2+1];
                    float r20 = q[2*Win2],  r21 = q[2*Win2+1];
                    float r30 = q[3*Win2],  r31 = q[3*Win2+1];
                    b0 += r00*wp[0] + r01*wp[1] + r10*wp[2] + r11*wp[3] + r20*wp[4] + r21*wp[5];
                    b1 += r10*wp[0] + r11*wp[1] + r20*wp[2] + r21*wp[3] + r30*wp[4] + r31*wp[5];
                }
                float m = fmaxf(b0, b1) + kb3[ci3];
                c3v[hr][wc] = fmaxf(m, 0.0f);
            }
        }
        const float* wp4 = k4 + ci3 * 6;
        a4_0 += c3v[0][0]*wp4[0] + c3v[0][1]*wp4[1] + c3v[1][0]*wp4[2]
              + c3v[1][1]*wp4[3] + c3v[2][0]*wp4[4] + c3v[2][1]*wp4[5];
        a4_1 += c3v[1][0]*wp4[0] + c3v[1][1]*wp4[1] + c3v[2][0]*wp4[2]
              + c3v[2][1]*wp4[3] + c3v[3][0]*wp4[4] + c3v[3][1]*wp4[5];
    }
    float m = fmaxf(a4_0, a4_1) + kb4[0];
    c4[t0] = fmaxf(m, 0.0f);
}

// ---- FC kernels: one wave per row, float4 loads ----
__global__ __launch_bounds__(256) void k_fc1(const float* __restrict__ v,
                                             const float* __restrict__ w,
                                             const float* __restrict__ b,
                                             float* __restrict__ out) {
    int wv = threadIdx.x >> 6, lane = threadIdx.x & 63;
    int o = blockIdx.x * 4 + wv;
    const float4* wr = (const float4*)(w + (size_t)o * 1680);
    const float4* vv = (const float4*)v;
    float s = 0.0f;
    for (int i = lane; i < 420; i += 64) {
        float4 a = vv[i], ww = wr[i];
        s += a.x*ww.x + a.y*ww.y + a.z*ww.z + a.w*ww.w;
    }
#pragma unroll
    for (int off = 32; off > 0; off >>= 1) s += __shfl_down(s, off, 64);
    if (lane == 0) out[o] = s + b[o];
}

__global__ __launch_bounds__(256) void k_fc1024(const float* __restrict__ v,
                                                const float* __restrict__ w,
                                                const float* __restrict__ b,
                                                float* __restrict__ out) {
    int wv = threadIdx.x >> 6, lane = threadIdx.x & 63;
    int o = blockIdx.x * 4 + wv;
    const float4* wr = (const float4*)(w + (size_t)o * 1024);
    const float4* vv = (const float4*)v;
    float s = 0.0f;
#pragma unroll
    for (int i = 0; i < 4; ++i) {
        float4 a = vv[lane + 64*i], ww = wr[lane + 64*i];
        s += a.x*ww.x + a.y*ww.y + a.z*ww.z + a.w*ww.w;
    }
#pragma unroll
    for (int off = 32; off > 0; off >>= 1) s += __shfl_down(s, off, 64);
    if (lane == 0) out[o] = s + b[o];
}

extern "C" void kernel_launch(void* const* d_in, const int* in_sizes, int n_in,
                              void* d_out, int out_size, void* d_ws, size_t ws_size,
                              hipStream_t stream) {
    const float* x   = (const float*)d_in[0];
    const int*   ei  = (const int*)d_in[1];
    const float* W1  = (const float*)d_in[2];
    const float* b1  = (const float*)d_in[3];
    const float* W2  = (const float*)d_in[4];
    const float* b2  = (const float*)d_in[5];
    const float* k1  = (const float*)d_in[6];
    const float* kb1 = (const float*)d_in[7];
    const float* k2  = (const float*)d_in[8];
    const float* kb2 = (const float*)d_in[9];
    const float* k3  = (const float*)d_in[10];
    const float* kb3 = (const float*)d_in[11];
    const float* k4  = (const float*)d_in[12];
    const float* kb4 = (const float*)d_in[13];
    const float* fw1 = (const float*)d_in[14];
    const float* fb1 = (const float*)d_in[15];
    const float* fw2 = (const float*)d_in[16];
    const float* fb2 = (const float*)d_in[17];
    const float* fw3 = (const float*)d_in[18];
    const float* fb3 = (const float*)d_in[19];

    int n = in_sizes[0] / 6;       // 1000
    int E = in_sizes[1] / 2;       // 8000
    const int* row = ei;
    const int* col = ei + E;

    float* ws   = (float*)d_ws;
    float* deg  = ws;              // 1024
    float* agg1 = ws + 1024;       // 32000 (agg1+agg2 contiguous for K1 zeroing)
    float* agg2 = agg1 + 32000;    // 32000
    float* xw   = agg2 + 32000;    // 32000
    float* c1   = xw + 32000;      // 3*499*31 = 46407
    float* c2   = c1 + 46407;      // 6*248*30 = 44640
    float* c4   = c2 + 44640;      // 1680
    float* f1   = c4 + 1696;       // 1024 (16B aligned: 1696*4 % 16 == 0)
    float* f2   = f1 + 1024;       // 1024

    const int B = 256;

    hipMemsetAsync(deg, 0, n * sizeof(float), stream);
    k1_prep<<<256, B, 0, stream>>>(x, col, W1, deg, agg1, xw, n, E);
    int st = (E + n) * 32;
    k_scatter<<<(st + B - 1) / B, B, 0, stream>>>(xw, deg, row, col, agg1, E, n);
    k3_xw2<<<(n * 32 + B - 1) / B, B, 0, stream>>>(agg1, b1, W2, xw, n);
    k_scatter<<<(st + B - 1) / B, B, 0, stream>>>(xw, deg, row, col, agg2, E, n);
    k5_conv1<<<(3 * 499 * 31 + B - 1) / B, B, 0, stream>>>(agg2, b2, k1, kb1, c1);
    k6_conv2<<<(6 * 248 * 30 + B - 1) / B, B, 0, stream>>>(c1, k2, kb2, c2);
    k7_conv34<<<(60 * 28 + B - 1) / B, B, 0, stream>>>(c2, k3, kb3, k4, kb4, c4);
    k_fc1<<<256, B, 0, stream>>>(c4, fw1, fb1, f1);
    k_fc1024<<<256, B, 0, stream>>>(f1, fw2, fb2, f2);
    k_fc1024<<<16, B, 0, stream>>>(f2, fw3, fb3, (float*)d_out);
}

// Round 5
// 133.814 us; speedup vs baseline: 3.0252x; 1.4005x over previous
//
#include <hip/hip_runtime.h>

#define LEAKY(v) ((v) > 0.0f ? (v) : 0.2f * (v))

// ---- K1: zero agg1/agg2, degree atomics (edges only; self-loop folded as +1),
//          xw1 = x@W1 (features 3..5 only; 0..2 zeroed by forward) ----
__global__ void k1_prep(const float* __restrict__ x, const int* __restrict__ col,
                        const float* __restrict__ W1, float* __restrict__ deg,
                        float* __restrict__ aggs /*agg1,agg2 contiguous*/,
                        float* __restrict__ xw, int n, int E) {
    int tid = blockIdx.x * blockDim.x + threadIdx.x;
    int NT = gridDim.x * blockDim.x;
    for (int i = tid; i < 2 * n * 32; i += NT) aggs[i] = 0.0f;
    for (int e = tid; e < E; e += NT) atomicAdd(&deg[col[e]], 1.0f);
    for (int t = tid; t < n * 32; t += NT) {
        int j = t & 31, nn = t >> 5;
        xw[t] = x[nn*6+3] * W1[96+j]
              + x[nn*6+4] * W1[128+j]
              + x[nn*6+5] * W1[160+j];
    }
}

// ---- scatter: agg[col] += xw[row] * rsqrt(deg[row]+1)*rsqrt(deg[col]+1),
//      incl. self-loops (e >= E) ----
__global__ void k_scatter(const float* __restrict__ xw, const float* __restrict__ deg,
                          const int* __restrict__ row, const int* __restrict__ col,
                          float* __restrict__ agg, int E, int n) {
    int tid = blockIdx.x * blockDim.x + threadIdx.x;
    int total = (E + n) * 32;
    if (tid >= total) return;
    int e = tid >> 5, j = tid & 31;
    int r, c; float nrm;
    if (e < E) {
        r = row[e]; c = col[e];
        nrm = (1.0f / sqrtf(deg[r] + 1.0f)) * (1.0f / sqrtf(deg[c] + 1.0f));
    } else {
        r = c = e - E;
        nrm = 1.0f / (deg[r] + 1.0f);
    }
    atomicAdd(&agg[c * 32 + j], xw[r * 32 + j] * nrm);
}

// ---- K3: xw = leaky(agg1 + b1) @ W2 ----
__global__ void k3_xw2(const float* __restrict__ agg1, const float* __restrict__ b1,
                       const float* __restrict__ W2, float* __restrict__ xw, int n) {
    int tid = blockIdx.x * blockDim.x + threadIdx.x;
    if (tid >= n * 32) return;
    int j = tid & 31, nn = tid >> 5;
    const float* a = agg1 + nn * 32;
    float s = 0.0f;
#pragma unroll
    for (int f = 0; f < 32; ++f) {
        float v = a[f] + b1[f];
        v = LEAKY(v);
        s += v * W2[f * 32 + j];
    }
    xw[tid] = s;
}

// ---- K5: conv1 (+b2, leaky on input) + relu + pool -> c1 [3,499,31] ----
__global__ void k5_conv1(const float* __restrict__ h2, const float* __restrict__ b2,
                         const float* __restrict__ w, const float* __restrict__ bias,
                         float* __restrict__ out) {
    const int Hp = 499, Wo = 31, total = 3 * Hp * Wo;
    int t0 = blockIdx.x * blockDim.x + threadIdx.x;
    if (t0 >= total) return;
    int ow = t0 % Wo; int t = t0 / Wo; int oh = t % Hp; int co = t / Hp;
    const float* ip = h2 + (2 * oh) * 32 + ow;
    float vals[4][2];
#pragma unroll
    for (int r = 0; r < 4; ++r)
#pragma unroll
        for (int cx = 0; cx < 2; ++cx) {
            float v = ip[r * 32 + cx] + b2[ow + cx];
            vals[r][cx] = LEAKY(v);
        }
    const float* wp = w + co * 6;
    float a0 = vals[0][0]*wp[0] + vals[0][1]*wp[1] + vals[1][0]*wp[2]
             + vals[1][1]*wp[3] + vals[2][0]*wp[4] + vals[2][1]*wp[5];
    float a1 = vals[1][0]*wp[0] + vals[1][1]*wp[1] + vals[2][0]*wp[2]
             + vals[2][1]*wp[3] + vals[3][0]*wp[4] + vals[3][1]*wp[5];
    float m = fmaxf(a0, a1) + bias[co];
    out[t0] = fmaxf(m, 0.0f);
}

// ---- K6: conv2 -> c2 [6,248,30] ----
__global__ void k6_conv2(const float* __restrict__ in, const float* __restrict__ w,
                         const float* __restrict__ bias, float* __restrict__ out) {
    const int CI = 3, Hin = 499, Win = 31, Hp = 248, Wo = 30, total = 6 * Hp * Wo;
    int t0 = blockIdx.x * blockDim.x + threadIdx.x;
    if (t0 >= total) return;
    int ow = t0 % Wo; int t = t0 / Wo; int oh = t % Hp; int co = t / Hp;
    float a0 = 0.0f, a1 = 0.0f;
#pragma unroll
    for (int ci = 0; ci < CI; ++ci) {
        const float* q = in + (ci * Hin + 2 * oh) * Win + ow;
        const float* wp = w + (co * CI + ci) * 6;
        float r00 = q[0],     r01 = q[1];
        float r10 = q[Win],   r11 = q[Win+1];
        float r20 = q[2*Win], r21 = q[2*Win+1];
        float r30 = q[3*Win], r31 = q[3*Win+1];
        a0 += r00*wp[0] + r01*wp[1] + r10*wp[2] + r11*wp[3] + r20*wp[4] + r21*wp[5];
        a1 += r10*wp[0] + r11*wp[1] + r20*wp[2] + r21*wp[3] + r30*wp[4] + r31*wp[5];
    }
    float m = fmaxf(a0, a1) + bias[co];
    out[t0] = fmaxf(m, 0.0f);
}

// ---- K7: conv3 -> c3 [3,123,29]; wide grid (42 blocks), one thread/output ----
__global__ void k7_conv3(const float* __restrict__ in, const float* __restrict__ w,
                         const float* __restrict__ bias, float* __restrict__ out) {
    const int CI = 6, Hin = 248, Win = 30, Hp = 123, Wo = 29, total = 3 * Hp * Wo;
    int t0 = blockIdx.x * blockDim.x + threadIdx.x;
    if (t0 >= total) return;
    int ow = t0 % Wo; int t = t0 / Wo; int oh = t % Hp; int co = t / Hp;
    float a0 = 0.0f, a1 = 0.0f;
#pragma unroll
    for (int ci = 0; ci < CI; ++ci) {
        const float* q = in + (ci * Hin + 2 * oh) * Win + ow;
        const float* wp = w + (co * CI + ci) * 6;
        float r00 = q[0],     r01 = q[1];
        float r10 = q[Win],   r11 = q[Win+1];
        float r20 = q[2*Win], r21 = q[2*Win+1];
        float r30 = q[3*Win], r31 = q[3*Win+1];
        a0 += r00*wp[0] + r01*wp[1] + r10*wp[2] + r11*wp[3] + r20*wp[4] + r21*wp[5];
        a1 += r10*wp[0] + r11*wp[1] + r20*wp[2] + r21*wp[3] + r30*wp[4] + r31*wp[5];
    }
    float m = fmaxf(a0, a1) + bias[co];
    out[t0] = fmaxf(m, 0.0f);
}

// ---- K8: conv4 (redundant per block, tiny: 48 loads + 36 FMA per output)
//          into LDS, then FC1 rows o = blockIdx*4 + wave ----
__global__ __launch_bounds__(256) void k8_conv4_fc1(
        const float* __restrict__ c3, const float* __restrict__ k4,
        const float* __restrict__ kb4, const float* __restrict__ fw1,
        const float* __restrict__ fb1, float* __restrict__ f1) {
    __shared__ __align__(16) float lc4[1680];
    const int Hin = 123, Win = 29, Wo = 28;
    float kb = kb4[0];
    for (int t0 = (int)threadIdx.x; t0 < 1680; t0 += 256) {
        int ow = t0 % Wo; int oh = t0 / Wo;
        float a0 = 0.0f, a1 = 0.0f;
#pragma unroll
        for (int ci = 0; ci < 3; ++ci) {
            const float* q = c3 + (ci * Hin + 2 * oh) * Win + ow;
            const float* wp = k4 + ci * 6;
            float r00 = q[0],     r01 = q[1];
            float r10 = q[Win],   r11 = q[Win+1];
            float r20 = q[2*Win], r21 = q[2*Win+1];
            float r30 = q[3*Win], r31 = q[3*Win+1];
            a0 += r00*wp[0] + r01*wp[1] + r10*wp[2] + r11*wp[3] + r20*wp[4] + r21*wp[5];
            a1 += r10*wp[0] + r11*wp[1] + r20*wp[2] + r21*wp[3] + r30*wp[4] + r31*wp[5];
        }
        float m = fmaxf(a0, a1) + kb;
        lc4[t0] = fmaxf(m, 0.0f);
    }
    __syncthreads();
    int wv = threadIdx.x >> 6, lane = threadIdx.x & 63;
    int o = blockIdx.x * 4 + wv;
    const float4* wr = (const float4*)(fw1 + (size_t)o * 1680);
    const float4* vv = (const float4*)lc4;
    float s = 0.0f;
    for (int i = lane; i < 420; i += 64) {
        float4 a = vv[i], ww = wr[i];
        s += a.x*ww.x + a.y*ww.y + a.z*ww.z + a.w*ww.w;
    }
#pragma unroll
    for (int off = 32; off > 0; off >>= 1) s += __shfl_down(s, off, 64);
    if (lane == 0) f1[o] = s + fb1[o];
}

// ---- FC 1024-in: one wave per row, float4 loads ----
__global__ __launch_bounds__(256) void k_fc1024(const float* __restrict__ v,
                                                const float* __restrict__ w,
                                                const float* __restrict__ b,
                                                float* __restrict__ out) {
    int wv = threadIdx.x >> 6, lane = threadIdx.x & 63;
    int o = blockIdx.x * 4 + wv;
    const float4* wr = (const float4*)(w + (size_t)o * 1024);
    const float4* vv = (const float4*)v;
    float s = 0.0f;
#pragma unroll
    for (int i = 0; i < 4; ++i) {
        float4 a = vv[lane + 64*i], ww = wr[lane + 64*i];
        s += a.x*ww.x + a.y*ww.y + a.z*ww.z + a.w*ww.w;
    }
#pragma unroll
    for (int off = 32; off > 0; off >>= 1) s += __shfl_down(s, off, 64);
    if (lane == 0) out[o] = s + b[o];
}

extern "C" void kernel_launch(void* const* d_in, const int* in_sizes, int n_in,
                              void* d_out, int out_size, void* d_ws, size_t ws_size,
                              hipStream_t stream) {
    const float* x   = (const float*)d_in[0];
    const int*   ei  = (const int*)d_in[1];
    const float* W1  = (const float*)d_in[2];
    const float* b1  = (const float*)d_in[3];
    const float* W2  = (const float*)d_in[4];
    const float* b2  = (const float*)d_in[5];
    const float* k1  = (const float*)d_in[6];
    const float* kb1 = (const float*)d_in[7];
    const float* k2  = (const float*)d_in[8];
    const float* kb2 = (const float*)d_in[9];
    const float* k3  = (const float*)d_in[10];
    const float* kb3 = (const float*)d_in[11];
    const float* k4  = (const float*)d_in[12];
    const float* kb4 = (const float*)d_in[13];
    const float* fw1 = (const float*)d_in[14];
    const float* fb1 = (const float*)d_in[15];
    const float* fw2 = (const float*)d_in[16];
    const float* fb2 = (const float*)d_in[17];
    const float* fw3 = (const float*)d_in[18];
    const float* fb3 = (const float*)d_in[19];

    int n = in_sizes[0] / 6;       // 1000
    int E = in_sizes[1] / 2;       // 8000
    const int* row = ei;
    const int* col = ei + E;

    float* ws   = (float*)d_ws;
    float* deg  = ws;              // 1024
    float* agg1 = ws + 1024;       // 32000 (agg1+agg2 contiguous for K1 zeroing)
    float* agg2 = agg1 + 32000;    // 32000
    float* xw   = agg2 + 32000;    // 32000
    float* c1   = xw + 32000;      // 3*499*31 = 46407
    float* c2   = c1 + 46407;      // 6*248*30 = 44640
    float* c3   = c2 + 44640;      // 3*123*29 = 10701
    float* f1   = c3 + 10704;      // 1024 (16B aligned)
    float* f2   = f1 + 1024;       // 1024

    const int B = 256;

    hipMemsetAsync(deg, 0, n * sizeof(float), stream);
    k1_prep<<<256, B, 0, stream>>>(x, col, W1, deg, agg1, xw, n, E);
    int st = (E + n) * 32;
    k_scatter<<<(st + B - 1) / B, B, 0, stream>>>(xw, deg, row, col, agg1, E, n);
    k3_xw2<<<(n * 32 + B - 1) / B, B, 0, stream>>>(agg1, b1, W2, xw, n);
    k_scatter<<<(st + B - 1) / B, B, 0, stream>>>(xw, deg, row, col, agg2, E, n);
    k5_conv1<<<(3 * 499 * 31 + B - 1) / B, B, 0, stream>>>(agg2, b2, k1, kb1, c1);
    k6_conv2<<<(6 * 248 * 30 + B - 1) / B, B, 0, stream>>>(c1, k2, kb2, c2);
    k7_conv3<<<(3 * 123 * 29 + B - 1) / B, B, 0, stream>>>(c2, k3, kb3, c3);
    k8_conv4_fc1<<<256, B, 0, stream>>>(c3, k4, kb4, fw1, fb1, f1);
    k_fc1024<<<256, B, 0, stream>>>(f1, fw2, fb2, f2);
    k_fc1024<<<16, B, 0, stream>>>(f2, fw3, fb3, (float*)d_out);
}